// Round 1
// baseline (2942.847 us; speedup 1.0000x reference)
//
#include <hip/hip_runtime.h>
#include <hip/hip_bf16.h>

// GCN link predictor:
//   z1 = relu(gcnconv(x, W1, b1)); z2 = gcnconv(z1, W2, b2)
//   pos/neg scores = rowwise dot of z2 gathered at edge endpoints.
// All fp32 (tolerance ~1.2e-4 relative forbids bf16 MFMA; CDNA4 has no fp32 MFMA).

__device__ __forceinline__ void atomAdd(float* p, float v) {
    __hip_atomic_fetch_add(p, v, __ATOMIC_RELAXED, __HIP_MEMORY_SCOPE_AGENT);
}

__global__ __launch_bounds__(256) void k_init_deg(float* deg, int n) {
    int i = blockIdx.x * 256 + threadIdx.x;
    if (i < n) deg[i] = 1.0f;   // self-loop
}

__global__ __launch_bounds__(256) void k_count_deg(const int* __restrict__ dst, float* deg, int E) {
    int e = blockIdx.x * 256 + threadIdx.x;
    if (e < E) atomAdd(&deg[dst[e]], 1.0f);
}

__global__ __launch_bounds__(256) void k_dinv(float* deg, int n) {
    int i = blockIdx.x * 256 + threadIdx.x;
    if (i < n) deg[i] = rsqrtf(deg[i]);   // in-place deg -> dinv
}

// Out[M,128] = (RELU ? relu(X) : X)[M,128] @ W[128,128]
// 256 threads, 128 rows/block. Thread (rgrp=tid>>3, cq=tid&7) computes rows
// rgrp*4..+3 x cols {4*(cq+8j)..+3, j=0..3} (4x16 micro-tile, 64 acc VGPRs).
// W staged in LDS (64KB exactly -> 2 blocks/CU). X read via L1 (8-fold bcast).
template <int RELU>
__global__ __launch_bounds__(256) void k_gemm128(const float* __restrict__ X,
                                                 const float* __restrict__ W,
                                                 float* __restrict__ Out, int M) {
    __shared__ float4 Wl[4096];  // [k=128][cgrp=32]
    const float4* W4 = reinterpret_cast<const float4*>(W);
    int tid = threadIdx.x;
#pragma unroll
    for (int i = 0; i < 16; i++) Wl[tid + 256 * i] = W4[tid + 256 * i];
    __syncthreads();

    int rgrp = tid >> 3, cq = tid & 7;
    long r0 = (long)blockIdx.x * 128 + rgrp * 4;
    float4 acc[4][4];
#pragma unroll
    for (int i = 0; i < 4; i++)
#pragma unroll
        for (int j = 0; j < 4; j++) acc[i][j] = make_float4(0.f, 0.f, 0.f, 0.f);

    const float4* X4 = reinterpret_cast<const float4*>(X);
    for (int kk = 0; kk < 32; ++kk) {
        float4 xv[4];
#pragma unroll
        for (int i = 0; i < 4; i++) {
            long r = r0 + i;
            if (r < M) {
                float4 v = X4[r * 32 + kk];
                if (RELU) {
                    v.x = fmaxf(v.x, 0.f); v.y = fmaxf(v.y, 0.f);
                    v.z = fmaxf(v.z, 0.f); v.w = fmaxf(v.w, 0.f);
                }
                xv[i] = v;
            } else {
                xv[i] = make_float4(0.f, 0.f, 0.f, 0.f);
            }
        }
#pragma unroll
        for (int l = 0; l < 4; l++) {
            float4 w[4];
#pragma unroll
            for (int j = 0; j < 4; j++) w[j] = Wl[(kk * 4 + l) * 32 + cq + 8 * j];
#pragma unroll
            for (int i = 0; i < 4; i++) {
                float xs = reinterpret_cast<const float*>(&xv[i])[l];
#pragma unroll
                for (int j = 0; j < 4; j++) {
                    acc[i][j].x = fmaf(xs, w[j].x, acc[i][j].x);
                    acc[i][j].y = fmaf(xs, w[j].y, acc[i][j].y);
                    acc[i][j].z = fmaf(xs, w[j].z, acc[i][j].z);
                    acc[i][j].w = fmaf(xs, w[j].w, acc[i][j].w);
                }
            }
        }
    }
    float4* O4 = reinterpret_cast<float4*>(Out);
#pragma unroll
    for (int i = 0; i < 4; i++) {
        long r = r0 + i;
        if (r < M) {
#pragma unroll
            for (int j = 0; j < 4; j++) O4[r * 32 + cq + 8 * j] = acc[i][j];
        }
    }
}

// agg[i] = H[i] * dinv[i]^2 + bias   (self-loop term + bias; init for atomics)
__global__ __launch_bounds__(256) void k_agg_init(const float4* __restrict__ H4,
                                                  const float* __restrict__ dinv,
                                                  const float* __restrict__ bias,
                                                  float4* __restrict__ out4, int n) {
    int i = blockIdx.x * 256 + threadIdx.x;
    if (i >= n * 32) return;
    int r = i >> 5, c4 = i & 31;
    float di = dinv[r];
    float w = di * di;
    float4 h = H4[i];
    float4 b = reinterpret_cast<const float4*>(bias)[c4];
    float4 o;
    o.x = fmaf(h.x, w, b.x); o.y = fmaf(h.y, w, b.y);
    o.z = fmaf(h.z, w, b.z); o.w = fmaf(h.w, w, b.w);
    out4[i] = o;
}

// agg[dst] += H[src] * dinv[src]*dinv[dst]; 32 threads (=1 float4 lane each) per edge
__global__ __launch_bounds__(256) void k_aggregate(const float4* __restrict__ H4,
                                                   const int* __restrict__ src,
                                                   const int* __restrict__ dst,
                                                   const float* __restrict__ dinv,
                                                   float* __restrict__ agg, int E) {
    int e = blockIdx.x * 8 + (threadIdx.x >> 5);
    if (e >= E) return;
    int c4 = threadIdx.x & 31;
    int s = src[e], d = dst[e];
    float w = dinv[s] * dinv[d];
    float4 v = H4[(long)s * 32 + c4];
    float* a = agg + (long)d * 128 + c4 * 4;
    atomAdd(a + 0, v.x * w);
    atomAdd(a + 1, v.y * w);
    atomAdd(a + 2, v.z * w);
    atomAdd(a + 3, v.w * w);
}

// One wave per pair: lane reads float2 of each endpoint row, shuffle-reduce.
__global__ __launch_bounds__(256) void k_score(const float2* __restrict__ Z2,
                                               const int* __restrict__ pe,
                                               const int* __restrict__ ne,
                                               float* __restrict__ out, int np) {
    int pair = blockIdx.x * 4 + (threadIdx.x >> 6);
    int lane = threadIdx.x & 63;
    if (pair >= 2 * np) return;
    const int* ei = pair < np ? pe : ne;
    int k = pair < np ? pair : pair - np;
    int a = ei[k], b = ei[k + np];
    float2 va = Z2[(long)a * 64 + lane];
    float2 vb = Z2[(long)b * 64 + lane];
    float s = fmaf(va.x, vb.x, va.y * vb.y);
#pragma unroll
    for (int o = 32; o > 0; o >>= 1) s += __shfl_down(s, o, 64);
    if (lane == 0) out[pair] = s;
}

extern "C" void kernel_launch(void* const* d_in, const int* in_sizes, int n_in,
                              void* d_out, int out_size, void* d_ws, size_t ws_size,
                              hipStream_t stream) {
    const float* x  = (const float*)d_in[0];
    const float* W1 = (const float*)d_in[1];
    const float* b1 = (const float*)d_in[2];
    const float* W2 = (const float*)d_in[3];
    const float* b2 = (const float*)d_in[4];
    const int* ei = (const int*)d_in[5];
    const int* pe = (const int*)d_in[6];
    const int* ne = (const int*)d_in[7];

    int n  = in_sizes[0] / 128;  // 50000
    int E  = in_sizes[5] / 2;    // 800000
    int np = in_sizes[6] / 2;    // 100000
    const int* src = ei;
    const int* dst = ei + E;

    float* ws   = (float*)d_ws;
    float* dinv = ws;                       // 50000 floats (deg -> dinv in place)
    float* H    = ws + 65536;               // 50000*128
    float* Z    = H + (size_t)n * 128;      // 50000*128
    float* out  = (float*)d_out;            // pos(100000) ++ neg(100000)

    dim3 B(256);
    k_init_deg<<<(n + 255) / 256, B, 0, stream>>>(dinv, n);
    k_count_deg<<<(E + 255) / 256, B, 0, stream>>>(dst, dinv, E);
    k_dinv<<<(n + 255) / 256, B, 0, stream>>>(dinv, n);

    int gblk = (n + 127) / 128;
    // layer 1
    k_gemm128<0><<<gblk, B, 0, stream>>>(x, W1, H, n);
    k_agg_init<<<(n * 32 + 255) / 256, B, 0, stream>>>((const float4*)H, dinv, b1, (float4*)Z, n);
    k_aggregate<<<(E + 7) / 8, B, 0, stream>>>((const float4*)H, src, dst, dinv, Z, E);
    // layer 2 (relu fused into GEMM2 load)
    k_gemm128<1><<<gblk, B, 0, stream>>>(Z, W2, H, n);
    k_agg_init<<<(n * 32 + 255) / 256, B, 0, stream>>>((const float4*)H, dinv, b2, (float4*)Z, n);
    k_aggregate<<<(E + 7) / 8, B, 0, stream>>>((const float4*)H, src, dst, dinv, Z, E);
    // scoring
    k_score<<<(2 * np + 3) / 4, B, 0, stream>>>((const float2*)Z, pe, ne, out, np);
}

// Round 3
// 426.026 us; speedup vs baseline: 6.9077x; 6.9077x over previous
//
#include <hip/hip_runtime.h>
#include <hip/hip_bf16.h>

// GCN link predictor, CSR-gather version:
//   build CSR by dst (histogram -> scan -> scatter)  [once per launch]
//   z1 = relu(gcn(x,W1,b1)); z2 = gcn(z1,W2,b2); scores = dot(z2[a], z2[b])
// All fp32 (tolerance ~1.2e-4 relative forbids bf16 MFMA; CDNA4 has no fp32 MFMA).
// Aggregation = per-node gather (wave per node), NO float atomics.

__global__ __launch_bounds__(256) void k_zero2(int* a, int* b, int n) {
    int i = blockIdx.x * 256 + threadIdx.x;
    if (i < n) { a[i] = 0; b[i] = 0; }
}

__global__ __launch_bounds__(256) void k_count(const int* __restrict__ dst, int* counts, int E) {
    int e = blockIdx.x * 256 + threadIdx.x;
    if (e < E) atomicAdd(&counts[dst[e]], 1);
}

__global__ __launch_bounds__(256) void k_dinv(const int* __restrict__ counts, float* dinv, int n) {
    int i = blockIdx.x * 256 + threadIdx.x;
    if (i < n) dinv[i] = rsqrtf((float)counts[i] + 1.0f);  // +1 self-loop
}

// ---- 3-kernel exclusive scan of counts[n] -> rowStart[n+1] (nb <= 256 blocks) ----
__global__ __launch_bounds__(256) void k_scan_block_reduce(const int* __restrict__ counts,
                                                           int* __restrict__ blockSum, int n) {
    __shared__ int s[256];
    int i = blockIdx.x * 256 + threadIdx.x;
    s[threadIdx.x] = i < n ? counts[i] : 0;
    __syncthreads();
#pragma unroll
    for (int o = 128; o > 0; o >>= 1) {
        if (threadIdx.x < o) s[threadIdx.x] += s[threadIdx.x + o];
        __syncthreads();
    }
    if (threadIdx.x == 0) blockSum[blockIdx.x] = s[0];
}

__global__ __launch_bounds__(256) void k_scan_blocksums(const int* __restrict__ blockSum,
                                                        int* __restrict__ blockOff,
                                                        int* __restrict__ rowStart,
                                                        int nb, int n, int E) {
    __shared__ int s[256];
    int t = threadIdx.x;
    int v = t < nb ? blockSum[t] : 0;
    s[t] = v;
    __syncthreads();
#pragma unroll
    for (int o = 1; o < 256; o <<= 1) {   // Hillis-Steele inclusive
        int add = t >= o ? s[t - o] : 0;
        __syncthreads();
        s[t] += add;
        __syncthreads();
    }
    if (t < nb) blockOff[t] = s[t] - v;   // exclusive
    if (t == 0) rowStart[n] = E;
}

__global__ __launch_bounds__(256) void k_scan_final(const int* __restrict__ counts,
                                                    const int* __restrict__ blockOff,
                                                    int* __restrict__ rowStart, int n) {
    __shared__ int s[256];
    int t = threadIdx.x;
    int i = blockIdx.x * 256 + t;
    int v = i < n ? counts[i] : 0;
    s[t] = v;
    __syncthreads();
#pragma unroll
    for (int o = 1; o < 256; o <<= 1) {
        int add = t >= o ? s[t - o] : 0;
        __syncthreads();
        s[t] += add;
        __syncthreads();
    }
    if (i < n) rowStart[i] = blockOff[blockIdx.x] + s[t] - v;  // exclusive
}

__global__ __launch_bounds__(256) void k_scatter(const int* __restrict__ src,
                                                 const int* __restrict__ dst,
                                                 const int* __restrict__ rowStart,
                                                 int* __restrict__ cursor,
                                                 int* __restrict__ csr_src, int E) {
    int e = blockIdx.x * 256 + threadIdx.x;
    if (e < E) {
        int d = dst[e];
        int pos = atomicAdd(&cursor[d], 1);
        csr_src[rowStart[d] + pos] = src[e];
    }
}

// Out[M,128] = (RELU ? relu(X) : X)[M,128] @ W[128,128]
// 256 threads, 128 rows/block; thread = 4x16 micro-tile; W in LDS (64KB).
template <int RELU>
__global__ __launch_bounds__(256) void k_gemm128(const float* __restrict__ X,
                                                 const float* __restrict__ W,
                                                 float* __restrict__ Out, int M) {
    __shared__ float4 Wl[4096];  // [k=128][cgrp=32]
    const float4* W4 = reinterpret_cast<const float4*>(W);
    int tid = threadIdx.x;
#pragma unroll
    for (int i = 0; i < 16; i++) Wl[tid + 256 * i] = W4[tid + 256 * i];
    __syncthreads();

    int rgrp = tid >> 3, cq = tid & 7;
    long r0 = (long)blockIdx.x * 128 + rgrp * 4;
    float4 acc[4][4];
#pragma unroll
    for (int i = 0; i < 4; i++)
#pragma unroll
        for (int j = 0; j < 4; j++) acc[i][j] = make_float4(0.f, 0.f, 0.f, 0.f);

    const float4* X4 = reinterpret_cast<const float4*>(X);
    for (int kk = 0; kk < 32; ++kk) {
        float4 xv[4];
#pragma unroll
        for (int i = 0; i < 4; i++) {
            long r = r0 + i;
            if (r < M) {
                float4 v = X4[r * 32 + kk];
                if (RELU) {
                    v.x = fmaxf(v.x, 0.f); v.y = fmaxf(v.y, 0.f);
                    v.z = fmaxf(v.z, 0.f); v.w = fmaxf(v.w, 0.f);
                }
                xv[i] = v;
            } else {
                xv[i] = make_float4(0.f, 0.f, 0.f, 0.f);
            }
        }
#pragma unroll
        for (int l = 0; l < 4; l++) {
            float4 w[4];
#pragma unroll
            for (int j = 0; j < 4; j++) w[j] = Wl[(kk * 4 + l) * 32 + cq + 8 * j];
#pragma unroll
            for (int i = 0; i < 4; i++) {
                float xs = reinterpret_cast<const float*>(&xv[i])[l];
#pragma unroll
                for (int j = 0; j < 4; j++) {
                    acc[i][j].x = fmaf(xs, w[j].x, acc[i][j].x);
                    acc[i][j].y = fmaf(xs, w[j].y, acc[i][j].y);
                    acc[i][j].z = fmaf(xs, w[j].z, acc[i][j].z);
                    acc[i][j].w = fmaf(xs, w[j].w, acc[i][j].w);
                }
            }
        }
    }
    float4* O4 = reinterpret_cast<float4*>(Out);
#pragma unroll
    for (int i = 0; i < 4; i++) {
        long r = r0 + i;
        if (r < M) {
#pragma unroll
            for (int j = 0; j < 4; j++) O4[r * 32 + cq + 8 * j] = acc[i][j];
        }
    }
}

// One wave per node: gather incident src rows via CSR, accumulate in regs.
// 64-edge chunks: coalesced index+weight load, then __shfl broadcast.
// Fuses self-loop term and bias. out = agg (pre-ReLU).
__global__ __launch_bounds__(256) void k_gather_agg(const float2* __restrict__ H2,
                                                    const int* __restrict__ rowStart,
                                                    const int* __restrict__ csr_src,
                                                    const float* __restrict__ dinv,
                                                    const float* __restrict__ bias,
                                                    float2* __restrict__ out2, int n) {
    int node = blockIdx.x * 4 + (threadIdx.x >> 6);
    if (node >= n) return;
    int lane = threadIdx.x & 63;
    int beg = rowStart[node], end = rowStart[node + 1];
    float dd = dinv[node];
    float2 acc = make_float2(0.f, 0.f);
    for (int j0 = beg; j0 < end; j0 += 64) {
        int m = end - j0;  // remaining (may exceed 64)
        int idx = 0;
        float w = 0.f;
        if (lane < m) {
            idx = csr_src[j0 + lane];
            w = dinv[idx];
        }
        int cnt = m < 64 ? m : 64;
        for (int t = 0; t < cnt; ++t) {
            int s = __shfl(idx, t, 64);
            float ws = __shfl(w, t, 64) * dd;
            float2 v = H2[(long)s * 64 + lane];
            acc.x = fmaf(v.x, ws, acc.x);
            acc.y = fmaf(v.y, ws, acc.y);
        }
    }
    // self-loop (norm = 1/deg = dd*dd) + bias
    float2 h = H2[(long)node * 64 + lane];
    float2 b = reinterpret_cast<const float2*>(bias)[lane];
    float w0 = dd * dd;
    acc.x = fmaf(h.x, w0, acc.x) + b.x;
    acc.y = fmaf(h.y, w0, acc.y) + b.y;
    out2[(long)node * 64 + lane] = acc;
}

// One wave per pair: lane reads float2 of each endpoint row, shuffle-reduce.
__global__ __launch_bounds__(256) void k_score(const float2* __restrict__ Z2,
                                               const int* __restrict__ pe,
                                               const int* __restrict__ ne,
                                               float* __restrict__ out, int np) {
    int pair = blockIdx.x * 4 + (threadIdx.x >> 6);
    int lane = threadIdx.x & 63;
    if (pair >= 2 * np) return;
    const int* ei = pair < np ? pe : ne;
    int k = pair < np ? pair : pair - np;
    int a = ei[k], b = ei[k + np];
    float2 va = Z2[(long)a * 64 + lane];
    float2 vb = Z2[(long)b * 64 + lane];
    float s = fmaf(va.x, vb.x, va.y * vb.y);
#pragma unroll
    for (int o = 32; o > 0; o >>= 1) s += __shfl_down(s, o, 64);
    if (lane == 0) out[pair] = s;
}

extern "C" void kernel_launch(void* const* d_in, const int* in_sizes, int n_in,
                              void* d_out, int out_size, void* d_ws, size_t ws_size,
                              hipStream_t stream) {
    const float* x  = (const float*)d_in[0];
    const float* W1 = (const float*)d_in[1];
    const float* b1 = (const float*)d_in[2];
    const float* W2 = (const float*)d_in[3];
    const float* b2 = (const float*)d_in[4];
    const int* ei = (const int*)d_in[5];
    const int* pe = (const int*)d_in[6];
    const int* ne = (const int*)d_in[7];

    int n  = in_sizes[0] / 128;  // 50000
    int E  = in_sizes[5] / 2;    // 800000
    int np = in_sizes[6] / 2;    // 100000
    const int* src = ei;
    const int* dst = ei + E;

    // workspace layout (4-byte elements, 16B-aligned sections)
    int* counts   = (int*)d_ws;               // n       (offset 0)
    int* cursor   = counts + 50048;           // n
    int* rowStart = cursor + 50048;           // n+1
    int* blockSum = rowStart + 50064;         // 256
    int* blockOff = blockSum + 256;           // 256
    int* csr_src  = blockOff + 256;           // E      (offset 150672)
    float* dinv   = (float*)(csr_src + 800000); // n    (offset 950672)
    float* H      = dinv + 50000;             // n*128  (offset 1000672)
    float* Z      = H + (size_t)n * 128;      // n*128
    float* out    = (float*)d_out;            // pos(np) ++ neg(np)

    dim3 B(256);
    int nb = (n + 255) / 256;  // 196 (<=256 required by k_scan_blocksums)

    // ---- CSR build + dinv ----
    k_zero2<<<nb, B, 0, stream>>>(counts, cursor, n);
    k_count<<<(E + 255) / 256, B, 0, stream>>>(dst, counts, E);
    k_dinv<<<nb, B, 0, stream>>>(counts, dinv, n);
    k_scan_block_reduce<<<nb, B, 0, stream>>>(counts, blockSum, n);
    k_scan_blocksums<<<1, B, 0, stream>>>(blockSum, blockOff, rowStart, nb, n, E);
    k_scan_final<<<nb, B, 0, stream>>>(counts, blockOff, rowStart, n);
    k_scatter<<<(E + 255) / 256, B, 0, stream>>>(src, dst, rowStart, cursor, csr_src, E);

    int gblk = (n + 127) / 128;
    int ablk = (n + 3) / 4;
    // layer 1
    k_gemm128<0><<<gblk, B, 0, stream>>>(x, W1, H, n);
    k_gather_agg<<<ablk, B, 0, stream>>>((const float2*)H, rowStart, csr_src, dinv, b1, (float2*)Z, n);
    // layer 2 (relu fused into GEMM2 load)
    k_gemm128<1><<<gblk, B, 0, stream>>>(Z, W2, H, n);
    k_gather_agg<<<ablk, B, 0, stream>>>((const float2*)H, rowStart, csr_src, dinv, b2, (float2*)Z, n);
    // scoring
    k_score<<<(2 * np + 3) / 4, B, 0, stream>>>((const float2*)Z, pe, ne, out, np);
}

// Round 8
// 390.488 us; speedup vs baseline: 7.5363x; 1.0910x over previous
//
#include <hip/hip_runtime.h>
#include <hip/hip_bf16.h>

// GCN link predictor, CSR-gather version, round 8 (R4-R7 resubmit; infra-only failures):
//   build CSR by dst (histogram -> scan -> scatter)  [every launch]
//   z1 = relu(gcn(x,W1,b1)); z2 = gcn(z1,W2,b2); scores = dot(z2[a], z2[b])
// All fp32 (tolerance ~1.2e-4 relative forbids bf16 MFMA; CDNA4 has no fp32 MFMA).
// Aggregation: wave per node, 4 edge-groups x 16 lanes (4 rows in flight).

__global__ __launch_bounds__(256) void k_zero(int* p, int n) {
    int i = blockIdx.x * 256 + threadIdx.x;
    if (i < n) p[i] = 0;
}

__global__ __launch_bounds__(256) void k_count(const int* __restrict__ dst, int* counts, int E) {
    int e = blockIdx.x * 256 + threadIdx.x;
    if (e < E) atomicAdd(&counts[dst[e]], 1);
}

// dinv[i] = rsqrt(deg+1), plus per-block sum of counts for the scan.
__global__ __launch_bounds__(256) void k_prep(const int* __restrict__ counts,
                                              float* __restrict__ dinv,
                                              int* __restrict__ blockSum, int n) {
    __shared__ int s[256];
    int i = blockIdx.x * 256 + threadIdx.x;
    int c = i < n ? counts[i] : 0;
    if (i < n) dinv[i] = rsqrtf((float)c + 1.0f);  // +1 self-loop
    s[threadIdx.x] = c;
    __syncthreads();
#pragma unroll
    for (int o = 128; o > 0; o >>= 1) {
        if (threadIdx.x < o) s[threadIdx.x] += s[threadIdx.x + o];
        __syncthreads();
    }
    if (threadIdx.x == 0) blockSum[blockIdx.x] = s[0];
}

__global__ __launch_bounds__(256) void k_scan_blocksums(const int* __restrict__ blockSum,
                                                        int* __restrict__ blockOff,
                                                        int* __restrict__ rowStart,
                                                        int nb, int n, int E) {
    __shared__ int s[256];
    int t = threadIdx.x;
    int v = t < nb ? blockSum[t] : 0;
    s[t] = v;
    __syncthreads();
#pragma unroll
    for (int o = 1; o < 256; o <<= 1) {   // Hillis-Steele inclusive
        int add = t >= o ? s[t - o] : 0;
        __syncthreads();
        s[t] += add;
        __syncthreads();
    }
    if (t < nb) blockOff[t] = s[t] - v;   // exclusive
    if (t == 0) rowStart[n] = E;
}

__global__ __launch_bounds__(256) void k_scan_final(const int* __restrict__ counts,
                                                    const int* __restrict__ blockOff,
                                                    int* __restrict__ rowStart, int n) {
    __shared__ int s[256];
    int t = threadIdx.x;
    int i = blockIdx.x * 256 + t;
    int v = i < n ? counts[i] : 0;
    s[t] = v;
    __syncthreads();
#pragma unroll
    for (int o = 1; o < 256; o <<= 1) {
        int add = t >= o ? s[t - o] : 0;
        __syncthreads();
        s[t] += add;
        __syncthreads();
    }
    if (i < n) rowStart[i] = blockOff[blockIdx.x] + s[t] - v;  // exclusive
}

__global__ __launch_bounds__(256) void k_scatter(const int* __restrict__ src,
                                                 const int* __restrict__ dst,
                                                 const int* __restrict__ rowStart,
                                                 int* __restrict__ cursor,
                                                 int* __restrict__ csr_src, int E) {
    int e = blockIdx.x * 256 + threadIdx.x;
    if (e < E) {
        int d = dst[e];
        int pos = atomicAdd(&cursor[d], 1);
        csr_src[rowStart[d] + pos] = src[e];
    }
}

// Out[M,128] = (RELU ? relu(X) : X)[M,128] @ W[128,128]
// 256 threads, 128 rows/block; thread = 4x16 micro-tile; W in LDS (64KB).
template <int RELU>
__global__ __launch_bounds__(256) void k_gemm128(const float* __restrict__ X,
                                                 const float* __restrict__ W,
                                                 float* __restrict__ Out, int M) {
    __shared__ float4 Wl[4096];  // [k=128][cgrp=32]
    const float4* W4 = reinterpret_cast<const float4*>(W);
    int tid = threadIdx.x;
#pragma unroll
    for (int i = 0; i < 16; i++) Wl[tid + 256 * i] = W4[tid + 256 * i];
    __syncthreads();

    int rgrp = tid >> 3, cq = tid & 7;
    long r0 = (long)blockIdx.x * 128 + rgrp * 4;
    float4 acc[4][4];
#pragma unroll
    for (int i = 0; i < 4; i++)
#pragma unroll
        for (int j = 0; j < 4; j++) acc[i][j] = make_float4(0.f, 0.f, 0.f, 0.f);

    const float4* X4 = reinterpret_cast<const float4*>(X);
    for (int kk = 0; kk < 32; ++kk) {
        float4 xv[4];
#pragma unroll
        for (int i = 0; i < 4; i++) {
            long r = r0 + i;
            if (r < M) {
                float4 v = X4[r * 32 + kk];
                if (RELU) {
                    v.x = fmaxf(v.x, 0.f); v.y = fmaxf(v.y, 0.f);
                    v.z = fmaxf(v.z, 0.f); v.w = fmaxf(v.w, 0.f);
                }
                xv[i] = v;
            } else {
                xv[i] = make_float4(0.f, 0.f, 0.f, 0.f);
            }
        }
#pragma unroll
        for (int l = 0; l < 4; l++) {
            float4 w[4];
#pragma unroll
            for (int j = 0; j < 4; j++) w[j] = Wl[(kk * 4 + l) * 32 + cq + 8 * j];
#pragma unroll
            for (int i = 0; i < 4; i++) {
                float xs = reinterpret_cast<const float*>(&xv[i])[l];
#pragma unroll
                for (int j = 0; j < 4; j++) {
                    acc[i][j].x = fmaf(xs, w[j].x, acc[i][j].x);
                    acc[i][j].y = fmaf(xs, w[j].y, acc[i][j].y);
                    acc[i][j].z = fmaf(xs, w[j].z, acc[i][j].z);
                    acc[i][j].w = fmaf(xs, w[j].w, acc[i][j].w);
                }
            }
        }
    }
    float4* O4 = reinterpret_cast<float4*>(Out);
#pragma unroll
    for (int i = 0; i < 4; i++) {
        long r = r0 + i;
        if (r < M) {
#pragma unroll
            for (int j = 0; j < 4; j++) O4[r * 32 + cq + 8 * j] = acc[i][j];
        }
    }
}

// Wave per node, 4 edge-groups x 16 lanes. Group g handles edge t*4+g each
// round; lane covers cols [cl*4..+3] and [64+cl*4..+3] (2x float4, coalesced
// 256B per group-half). 4 rows (2KB) in flight per wave. Cross-group reduce
// via 2 shfl_xor rounds. Fuses self-loop term and bias.
__global__ __launch_bounds__(256) void k_gather_agg(const float4* __restrict__ H4,
                                                    const int* __restrict__ rowStart,
                                                    const int* __restrict__ csr_src,
                                                    const float* __restrict__ dinv,
                                                    const float* __restrict__ bias,
                                                    float4* __restrict__ out4, int n) {
    int node = blockIdx.x * 4 + (threadIdx.x >> 6);
    if (node >= n) return;
    int lane = threadIdx.x & 63;
    int g = lane >> 4, cl = lane & 15;
    int beg = rowStart[node], end = rowStart[node + 1];
    float dd = dinv[node];
    float4 a0 = make_float4(0.f, 0.f, 0.f, 0.f);
    float4 a1 = make_float4(0.f, 0.f, 0.f, 0.f);

    for (int j0 = beg; j0 < end; j0 += 64) {
        int m = end - j0;
        if (m > 64) m = 64;
        int idx = 0;
        float w = 0.f;
        if (lane < m) {
            idx = csr_src[j0 + lane];
            w = dinv[idx];
        }
        int rounds = (m + 3) >> 2;
        for (int t = 0; t < rounds; ++t) {
            int e = t * 4 + g;
            int s = __shfl(idx, e, 64);
            float ws = __shfl(w, e, 64) * dd;
            if (e < m) {
                const float4* row = H4 + (long)s * 32;
                float4 v0 = row[cl];
                float4 v1 = row[cl + 16];
                a0.x = fmaf(v0.x, ws, a0.x); a0.y = fmaf(v0.y, ws, a0.y);
                a0.z = fmaf(v0.z, ws, a0.z); a0.w = fmaf(v0.w, ws, a0.w);
                a1.x = fmaf(v1.x, ws, a1.x); a1.y = fmaf(v1.y, ws, a1.y);
                a1.z = fmaf(v1.z, ws, a1.z); a1.w = fmaf(v1.w, ws, a1.w);
            }
        }
    }
    // reduce across the 4 groups (offsets 16, 32)
#pragma unroll
    for (int off = 16; off < 64; off <<= 1) {
        a0.x += __shfl_xor(a0.x, off, 64); a0.y += __shfl_xor(a0.y, off, 64);
        a0.z += __shfl_xor(a0.z, off, 64); a0.w += __shfl_xor(a0.w, off, 64);
        a1.x += __shfl_xor(a1.x, off, 64); a1.y += __shfl_xor(a1.y, off, 64);
        a1.z += __shfl_xor(a1.z, off, 64); a1.w += __shfl_xor(a1.w, off, 64);
    }
    if (g == 0) {
        const float4* row = H4 + (long)node * 32;
        const float4* B4 = reinterpret_cast<const float4*>(bias);
        float4 h0 = row[cl], h1 = row[cl + 16];
        float4 b0 = B4[cl], b1 = B4[cl + 16];
        float w0 = dd * dd;
        float4 o0, o1;
        o0.x = fmaf(h0.x, w0, a0.x) + b0.x; o0.y = fmaf(h0.y, w0, a0.y) + b0.y;
        o0.z = fmaf(h0.z, w0, a0.z) + b0.z; o0.w = fmaf(h0.w, w0, a0.w) + b0.w;
        o1.x = fmaf(h1.x, w0, a1.x) + b1.x; o1.y = fmaf(h1.y, w0, a1.y) + b1.y;
        o1.z = fmaf(h1.z, w0, a1.z) + b1.z; o1.w = fmaf(h1.w, w0, a1.w) + b1.w;
        out4[(long)node * 32 + cl] = o0;
        out4[(long)node * 32 + cl + 16] = o1;
    }
}

// 16 lanes per pair (4 pairs/wave, 8 rows in flight): lane reads 2x float4 of
// each endpoint row, 4-step shfl_xor reduce within the 16-lane group.
__global__ __launch_bounds__(256) void k_score(const float4* __restrict__ Z4,
                                               const int* __restrict__ pe,
                                               const int* __restrict__ ne,
                                               float* __restrict__ out, int np) {
    int pair = blockIdx.x * 16 + (threadIdx.x >> 4);
    if (pair >= 2 * np) return;
    int cl = threadIdx.x & 15;
    const int* ei = pair < np ? pe : ne;
    int k = pair < np ? pair : pair - np;
    int a = ei[k], b = ei[k + np];
    float4 va0 = Z4[(long)a * 32 + cl], va1 = Z4[(long)a * 32 + cl + 16];
    float4 vb0 = Z4[(long)b * 32 + cl], vb1 = Z4[(long)b * 32 + cl + 16];
    float s = va0.x * vb0.x;
    s = fmaf(va0.y, vb0.y, s); s = fmaf(va0.z, vb0.z, s); s = fmaf(va0.w, vb0.w, s);
    s = fmaf(va1.x, vb1.x, s); s = fmaf(va1.y, vb1.y, s);
    s = fmaf(va1.z, vb1.z, s); s = fmaf(va1.w, vb1.w, s);
#pragma unroll
    for (int o = 1; o < 16; o <<= 1) s += __shfl_xor(s, o, 64);
    if (cl == 0) out[pair] = s;
}

extern "C" void kernel_launch(void* const* d_in, const int* in_sizes, int n_in,
                              void* d_out, int out_size, void* d_ws, size_t ws_size,
                              hipStream_t stream) {
    const float* x  = (const float*)d_in[0];
    const float* W1 = (const float*)d_in[1];
    const float* b1 = (const float*)d_in[2];
    const float* W2 = (const float*)d_in[3];
    const float* b2 = (const float*)d_in[4];
    const int* ei = (const int*)d_in[5];
    const int* pe = (const int*)d_in[6];
    const int* ne = (const int*)d_in[7];

    int n  = in_sizes[0] / 128;  // 50000
    int E  = in_sizes[5] / 2;    // 800000
    int np = in_sizes[6] / 2;    // 100000
    const int* src = ei;
    const int* dst = ei + E;

    // workspace layout (4-byte elements, 16B-aligned sections)
    int* counts   = (int*)d_ws;               // n      (offset 0)
    int* cursor   = counts + 50048;           // n      (adjacent: one zero pass)
    int* rowStart = cursor + 50048;           // n+1
    int* blockSum = rowStart + 50064;         // 256
    int* blockOff = blockSum + 256;           // 256
    int* csr_src  = blockOff + 256;           // E
    float* dinv   = (float*)(csr_src + 800000); // n
    float* H      = dinv + 50000;             // n*128
    float* Z      = H + (size_t)n * 128;      // n*128
    float* out    = (float*)d_out;            // pos(np) ++ neg(np)

    dim3 B(256);
    int nb = (n + 255) / 256;  // 196 (<=256 required by k_scan_blocksums)

    // ---- CSR build + dinv ----
    k_zero<<<(2 * 50048 + 255) / 256, B, 0, stream>>>(counts, 2 * 50048);
    k_count<<<(E + 255) / 256, B, 0, stream>>>(dst, counts, E);
    k_prep<<<nb, B, 0, stream>>>(counts, dinv, blockSum, n);
    k_scan_blocksums<<<1, B, 0, stream>>>(blockSum, blockOff, rowStart, nb, n, E);
    k_scan_final<<<nb, B, 0, stream>>>(counts, blockOff, rowStart, n);
    k_scatter<<<(E + 255) / 256, B, 0, stream>>>(src, dst, rowStart, cursor, csr_src, E);

    int gblk = (n + 127) / 128;
    int ablk = (n + 3) / 4;
    // layer 1
    k_gemm128<0><<<gblk, B, 0, stream>>>(x, W1, H, n);
    k_gather_agg<<<ablk, B, 0, stream>>>((const float4*)H, rowStart, csr_src, dinv, b1, (float4*)Z, n);
    // layer 2 (relu fused into GEMM2 load)
    k_gemm128<1><<<gblk, B, 0, stream>>>(Z, W2, H, n);
    k_gather_agg<<<ablk, B, 0, stream>>>((const float4*)H, rowStart, csr_src, dinv, b2, (float4*)Z, n);
    // scoring
    k_score<<<(2 * np + 15) / 16, B, 0, stream>>>((const float4*)Z, pe, ne, out, np);
}

// Round 9
// 383.796 us; speedup vs baseline: 7.6677x; 1.0174x over previous
//
#include <hip/hip_runtime.h>
#include <hip/hip_bf16.h>

// GCN link predictor, CSR-gather, round 9:
//   CSR build (histogram -> scan -> scatter w/ fused edge weight) every launch
//   z1 = relu(gcn(x,W1,b1)); z2 = gcn(z1,W2,b2); scores = dot(z2[a], z2[b])
// All fp32 (tolerance ~1.2e-4 relative forbids bf16; CDNA4 has no fp32 MFMA).
// Gather: wave/node, 4 edge-groups x 16 lanes, register-pipelined (depth 2),
// mask-free rounds via weight=0 padding.

__global__ __launch_bounds__(256) void k_zero(int* p, int n) {
    int i = blockIdx.x * 256 + threadIdx.x;
    if (i < n) p[i] = 0;
}

__global__ __launch_bounds__(256) void k_count(const int* __restrict__ dst, int* counts, int E) {
    int e = blockIdx.x * 256 + threadIdx.x;
    if (e < E) atomicAdd(&counts[dst[e]], 1);
}

// dinv[i] = rsqrt(deg+1), plus per-block sum of counts for the scan.
__global__ __launch_bounds__(256) void k_prep(const int* __restrict__ counts,
                                              float* __restrict__ dinv,
                                              int* __restrict__ blockSum, int n) {
    __shared__ int s[256];
    int i = blockIdx.x * 256 + threadIdx.x;
    int c = i < n ? counts[i] : 0;
    if (i < n) dinv[i] = rsqrtf((float)c + 1.0f);  // +1 self-loop
    s[threadIdx.x] = c;
    __syncthreads();
#pragma unroll
    for (int o = 128; o > 0; o >>= 1) {
        if (threadIdx.x < o) s[threadIdx.x] += s[threadIdx.x + o];
        __syncthreads();
    }
    if (threadIdx.x == 0) blockSum[blockIdx.x] = s[0];
}

__global__ __launch_bounds__(256) void k_scan_blocksums(const int* __restrict__ blockSum,
                                                        int* __restrict__ blockOff,
                                                        int* __restrict__ rowStart,
                                                        int nb, int n, int E) {
    __shared__ int s[256];
    int t = threadIdx.x;
    int v = t < nb ? blockSum[t] : 0;
    s[t] = v;
    __syncthreads();
#pragma unroll
    for (int o = 1; o < 256; o <<= 1) {   // Hillis-Steele inclusive
        int add = t >= o ? s[t - o] : 0;
        __syncthreads();
        s[t] += add;
        __syncthreads();
    }
    if (t < nb) blockOff[t] = s[t] - v;   // exclusive
    if (t == 0) rowStart[n] = E;
}

__global__ __launch_bounds__(256) void k_scan_final(const int* __restrict__ counts,
                                                    const int* __restrict__ blockOff,
                                                    int* __restrict__ rowStart, int n) {
    __shared__ int s[256];
    int t = threadIdx.x;
    int i = blockIdx.x * 256 + t;
    int v = i < n ? counts[i] : 0;
    s[t] = v;
    __syncthreads();
#pragma unroll
    for (int o = 1; o < 256; o <<= 1) {
        int add = t >= o ? s[t - o] : 0;
        __syncthreads();
        s[t] += add;
        __syncthreads();
    }
    if (i < n) rowStart[i] = blockOff[blockIdx.x] + s[t] - v;  // exclusive
}

// Scatter edge -> CSR slot, fusing the symmetric norm dinv[s]*dinv[d] so the
// gather needs no random dinv lookup.
__global__ __launch_bounds__(256) void k_scatter(const int* __restrict__ src,
                                                 const int* __restrict__ dst,
                                                 const int* __restrict__ rowStart,
                                                 int* __restrict__ cursor,
                                                 const float* __restrict__ dinv,
                                                 int2* __restrict__ csr_ew, int E) {
    int e = blockIdx.x * 256 + threadIdx.x;
    if (e < E) {
        int s = src[e], d = dst[e];
        int pos = atomicAdd(&cursor[d], 1);
        float nw = dinv[s] * dinv[d];
        csr_ew[rowStart[d] + pos] = make_int2(s, __float_as_int(nw));
    }
}

// Out[M,128] = (RELU ? relu(X) : X)[M,128] @ W[128,128]
// 256 threads, 128 rows/block; thread = 4x16 micro-tile; W in LDS (64KB).
template <int RELU>
__global__ __launch_bounds__(256) void k_gemm128(const float* __restrict__ X,
                                                 const float* __restrict__ W,
                                                 float* __restrict__ Out, int M) {
    __shared__ float4 Wl[4096];  // [k=128][cgrp=32]
    const float4* W4 = reinterpret_cast<const float4*>(W);
    int tid = threadIdx.x;
#pragma unroll
    for (int i = 0; i < 16; i++) Wl[tid + 256 * i] = W4[tid + 256 * i];
    __syncthreads();

    int rgrp = tid >> 3, cq = tid & 7;
    long r0 = (long)blockIdx.x * 128 + rgrp * 4;
    float4 acc[4][4];
#pragma unroll
    for (int i = 0; i < 4; i++)
#pragma unroll
        for (int j = 0; j < 4; j++) acc[i][j] = make_float4(0.f, 0.f, 0.f, 0.f);

    const float4* X4 = reinterpret_cast<const float4*>(X);
    for (int kk = 0; kk < 32; ++kk) {
        float4 xv[4];
#pragma unroll
        for (int i = 0; i < 4; i++) {
            long r = r0 + i;
            if (r < M) {
                float4 v = X4[r * 32 + kk];
                if (RELU) {
                    v.x = fmaxf(v.x, 0.f); v.y = fmaxf(v.y, 0.f);
                    v.z = fmaxf(v.z, 0.f); v.w = fmaxf(v.w, 0.f);
                }
                xv[i] = v;
            } else {
                xv[i] = make_float4(0.f, 0.f, 0.f, 0.f);
            }
        }
#pragma unroll
        for (int l = 0; l < 4; l++) {
            float4 w[4];
#pragma unroll
            for (int j = 0; j < 4; j++) w[j] = Wl[(kk * 4 + l) * 32 + cq + 8 * j];
#pragma unroll
            for (int i = 0; i < 4; i++) {
                float xs = reinterpret_cast<const float*>(&xv[i])[l];
#pragma unroll
                for (int j = 0; j < 4; j++) {
                    acc[i][j].x = fmaf(xs, w[j].x, acc[i][j].x);
                    acc[i][j].y = fmaf(xs, w[j].y, acc[i][j].y);
                    acc[i][j].z = fmaf(xs, w[j].z, acc[i][j].z);
                    acc[i][j].w = fmaf(xs, w[j].w, acc[i][j].w);
                }
            }
        }
    }
    float4* O4 = reinterpret_cast<float4*>(Out);
#pragma unroll
    for (int i = 0; i < 4; i++) {
        long r = r0 + i;
        if (r < M) {
#pragma unroll
            for (int j = 0; j < 4; j++) O4[r * 32 + cq + 8 * j] = acc[i][j];
        }
    }
}

// Wave per node, 4 edge-groups x 16 lanes, software-pipelined depth 2.
// Invalid edge slots carry weight 0 (and index 0) so every round is
// mask-free: loads of row 0 are harmless, FMA adds 0. Round t+1's loads are
// issued before round t's accumulate -> vmcnt(2) overlap across rounds.
__global__ __launch_bounds__(256) void k_gather_agg(const float4* __restrict__ H4,
                                                    const int* __restrict__ rowStart,
                                                    const int2* __restrict__ csr_ew,
                                                    const float* __restrict__ dinv,
                                                    const float* __restrict__ bias,
                                                    float4* __restrict__ out4, int n) {
    int node = blockIdx.x * 4 + (threadIdx.x >> 6);
    if (node >= n) return;
    int lane = threadIdx.x & 63;
    int g = lane >> 4, cl = lane & 15;
    int beg = rowStart[node], end = rowStart[node + 1];
    float dd = dinv[node];
    float4 a0 = make_float4(0.f, 0.f, 0.f, 0.f);
    float4 a1 = make_float4(0.f, 0.f, 0.f, 0.f);

    for (int j0 = beg; j0 < end; j0 += 64) {
        int m = end - j0;
        if (m > 64) m = 64;
        int idx = 0;
        float w = 0.f;
        if (lane < m) {
            int2 ew = csr_ew[j0 + lane];
            idx = ew.x;
            w = __int_as_float(ew.y);
        }
        int rounds = (m + 3) >> 2;
        // prologue: round 0 loads
        int s = __shfl(idx, g, 64);
        float ws = __shfl(w, g, 64);
        const float4* row = H4 + (long)s * 32;
        float4 p0 = row[cl];
        float4 p1 = row[cl + 16];
        for (int t = 1; t < rounds; ++t) {
            int e2 = t * 4 + g;
            int s2 = __shfl(idx, e2, 64);
            float ws2 = __shfl(w, e2, 64);
            const float4* row2 = H4 + (long)s2 * 32;
            float4 q0 = row2[cl];          // issued before consuming p0/p1
            float4 q1 = row2[cl + 16];
            a0.x = fmaf(p0.x, ws, a0.x); a0.y = fmaf(p0.y, ws, a0.y);
            a0.z = fmaf(p0.z, ws, a0.z); a0.w = fmaf(p0.w, ws, a0.w);
            a1.x = fmaf(p1.x, ws, a1.x); a1.y = fmaf(p1.y, ws, a1.y);
            a1.z = fmaf(p1.z, ws, a1.z); a1.w = fmaf(p1.w, ws, a1.w);
            p0 = q0; p1 = q1; ws = ws2;
        }
        a0.x = fmaf(p0.x, ws, a0.x); a0.y = fmaf(p0.y, ws, a0.y);
        a0.z = fmaf(p0.z, ws, a0.z); a0.w = fmaf(p0.w, ws, a0.w);
        a1.x = fmaf(p1.x, ws, a1.x); a1.y = fmaf(p1.y, ws, a1.y);
        a1.z = fmaf(p1.z, ws, a1.z); a1.w = fmaf(p1.w, ws, a1.w);
    }
    // reduce across the 4 groups (offsets 16, 32)
#pragma unroll
    for (int off = 16; off < 64; off <<= 1) {
        a0.x += __shfl_xor(a0.x, off, 64); a0.y += __shfl_xor(a0.y, off, 64);
        a0.z += __shfl_xor(a0.z, off, 64); a0.w += __shfl_xor(a0.w, off, 64);
        a1.x += __shfl_xor(a1.x, off, 64); a1.y += __shfl_xor(a1.y, off, 64);
        a1.z += __shfl_xor(a1.z, off, 64); a1.w += __shfl_xor(a1.w, off, 64);
    }
    if (g == 0) {
        const float4* row = H4 + (long)node * 32;
        const float4* B4 = reinterpret_cast<const float4*>(bias);
        float4 h0 = row[cl], h1 = row[cl + 16];
        float4 b0 = B4[cl], b1 = B4[cl + 16];
        float w0 = dd * dd;   // self-loop norm = 1/deg
        float4 o0, o1;
        o0.x = fmaf(h0.x, w0, a0.x) + b0.x; o0.y = fmaf(h0.y, w0, a0.y) + b0.y;
        o0.z = fmaf(h0.z, w0, a0.z) + b0.z; o0.w = fmaf(h0.w, w0, a0.w) + b0.w;
        o1.x = fmaf(h1.x, w0, a1.x) + b1.x; o1.y = fmaf(h1.y, w0, a1.y) + b1.y;
        o1.z = fmaf(h1.z, w0, a1.z) + b1.z; o1.w = fmaf(h1.w, w0, a1.w) + b1.w;
        out4[(long)node * 32 + cl] = o0;
        out4[(long)node * 32 + cl + 16] = o1;
    }
}

// 16 lanes per pair (4 pairs/wave, 8 rows in flight): lane reads 2x float4 of
// each endpoint row, 4-step shfl_xor reduce within the 16-lane group.
__global__ __launch_bounds__(256) void k_score(const float4* __restrict__ Z4,
                                               const int* __restrict__ pe,
                                               const int* __restrict__ ne,
                                               float* __restrict__ out, int np) {
    int pair = blockIdx.x * 16 + (threadIdx.x >> 4);
    if (pair >= 2 * np) return;
    int cl = threadIdx.x & 15;
    const int* ei = pair < np ? pe : ne;
    int k = pair < np ? pair : pair - np;
    int a = ei[k], b = ei[k + np];
    float4 va0 = Z4[(long)a * 32 + cl], va1 = Z4[(long)a * 32 + cl + 16];
    float4 vb0 = Z4[(long)b * 32 + cl], vb1 = Z4[(long)b * 32 + cl + 16];
    float s = va0.x * vb0.x;
    s = fmaf(va0.y, vb0.y, s); s = fmaf(va0.z, vb0.z, s); s = fmaf(va0.w, vb0.w, s);
    s = fmaf(va1.x, vb1.x, s); s = fmaf(va1.y, vb1.y, s);
    s = fmaf(va1.z, vb1.z, s); s = fmaf(va1.w, vb1.w, s);
#pragma unroll
    for (int o = 1; o < 16; o <<= 1) s += __shfl_xor(s, o, 64);
    if (cl == 0) out[pair] = s;
}

extern "C" void kernel_launch(void* const* d_in, const int* in_sizes, int n_in,
                              void* d_out, int out_size, void* d_ws, size_t ws_size,
                              hipStream_t stream) {
    const float* x  = (const float*)d_in[0];
    const float* W1 = (const float*)d_in[1];
    const float* b1 = (const float*)d_in[2];
    const float* W2 = (const float*)d_in[3];
    const float* b2 = (const float*)d_in[4];
    const int* ei = (const int*)d_in[5];
    const int* pe = (const int*)d_in[6];
    const int* ne = (const int*)d_in[7];

    int n  = in_sizes[0] / 128;  // 50000
    int E  = in_sizes[5] / 2;    // 800000
    int np = in_sizes[6] / 2;    // 100000
    const int* src = ei;
    const int* dst = ei + E;

    // workspace layout (4-byte elements, 16B-aligned sections)
    int* counts   = (int*)d_ws;                 // n
    int* cursor   = counts + 50048;             // n   (adjacent: one zero pass)
    int* rowStart = cursor + 50048;             // n+1
    int* blockSum = rowStart + 50064;           // 256
    int* blockOff = blockSum + 256;             // 256
    int2* csr_ew  = (int2*)(blockOff + 256);    // E int2 (8B-aligned: 150672*4 % 8 == 0)
    float* dinv   = (float*)(csr_ew + 800000);  // n
    float* H      = dinv + 50000;               // n*128
    float* Z      = H + (size_t)n * 128;        // n*128
    float* out    = (float*)d_out;              // pos(np) ++ neg(np)

    dim3 B(256);
    int nb = (n + 255) / 256;  // 196 (<=256 required by k_scan_blocksums)

    // ---- CSR build + dinv ----
    k_zero<<<(2 * 50048 + 255) / 256, B, 0, stream>>>(counts, 2 * 50048);
    k_count<<<(E + 255) / 256, B, 0, stream>>>(dst, counts, E);
    k_prep<<<nb, B, 0, stream>>>(counts, dinv, blockSum, n);
    k_scan_blocksums<<<1, B, 0, stream>>>(blockSum, blockOff, rowStart, nb, n, E);
    k_scan_final<<<nb, B, 0, stream>>>(counts, blockOff, rowStart, n);
    k_scatter<<<(E + 255) / 256, B, 0, stream>>>(src, dst, rowStart, cursor, dinv, csr_ew, E);

    int gblk = (n + 127) / 128;
    int ablk = (n + 3) / 4;
    // layer 1
    k_gemm128<0><<<gblk, B, 0, stream>>>(x, W1, H, n);
    k_gather_agg<<<ablk, B, 0, stream>>>((const float4*)H, rowStart, csr_ew, dinv, b1, (float4*)Z, n);
    // layer 2 (relu fused into GEMM2 load)
    k_gemm128<1><<<gblk, B, 0, stream>>>(Z, W2, H, n);
    k_gather_agg<<<ablk, B, 0, stream>>>((const float4*)H, rowStart, csr_ew, dinv, b2, (float4*)Z, n);
    // scoring
    k_score<<<(2 * np + 15) / 16, B, 0, stream>>>((const float4*)Z, pe, ne, out, np);
}

// Round 11
// 338.850 us; speedup vs baseline: 8.6848x; 1.1326x over previous
//
#include <hip/hip_runtime.h>
#include <hip/hip_bf16.h>
#include <hip/hip_fp16.h>

// GCN link predictor, CSR-gather, round 11 (R10 resubmit; infra-only failure):
//   CSR build (histogram -> scan -> scatter w/ fused edge weight) every launch
//   z1 = relu(gcn(x,W1,b1)); z2 = gcn(z1,W2,b2); scores = dot(z2[a], z2[b])
// Gather inputs H1/H2 stored FP16 (halves the irreducible 8x-XCD-replicated
// fetch of random rows: R9 showed FETCH ~= 8*sizeof(H) at a ~3.7 TB/s
// beyond-L2 ceiling, insensitive to latency restructuring). All accumulation,
// Z1 (gemm2 input), Z2 (score input) stay fp32.

__global__ __launch_bounds__(256) void k_zero(int* p, int n) {
    int i = blockIdx.x * 256 + threadIdx.x;
    if (i < n) p[i] = 0;
}

__global__ __launch_bounds__(256) void k_count(const int* __restrict__ dst, int* counts, int E) {
    int e = blockIdx.x * 256 + threadIdx.x;
    if (e < E) atomicAdd(&counts[dst[e]], 1);
}

// dinv[i] = rsqrt(deg+1), plus per-block sum of counts for the scan.
__global__ __launch_bounds__(256) void k_prep(const int* __restrict__ counts,
                                              float* __restrict__ dinv,
                                              int* __restrict__ blockSum, int n) {
    __shared__ int s[256];
    int i = blockIdx.x * 256 + threadIdx.x;
    int c = i < n ? counts[i] : 0;
    if (i < n) dinv[i] = rsqrtf((float)c + 1.0f);  // +1 self-loop
    s[threadIdx.x] = c;
    __syncthreads();
#pragma unroll
    for (int o = 128; o > 0; o >>= 1) {
        if (threadIdx.x < o) s[threadIdx.x] += s[threadIdx.x + o];
        __syncthreads();
    }
    if (threadIdx.x == 0) blockSum[blockIdx.x] = s[0];
}

__global__ __launch_bounds__(256) void k_scan_blocksums(const int* __restrict__ blockSum,
                                                        int* __restrict__ blockOff,
                                                        int* __restrict__ rowStart,
                                                        int nb, int n, int E) {
    __shared__ int s[256];
    int t = threadIdx.x;
    int v = t < nb ? blockSum[t] : 0;
    s[t] = v;
    __syncthreads();
#pragma unroll
    for (int o = 1; o < 256; o <<= 1) {   // Hillis-Steele inclusive
        int add = t >= o ? s[t - o] : 0;
        __syncthreads();
        s[t] += add;
        __syncthreads();
    }
    if (t < nb) blockOff[t] = s[t] - v;   // exclusive
    if (t == 0) rowStart[n] = E;
}

__global__ __launch_bounds__(256) void k_scan_final(const int* __restrict__ counts,
                                                    const int* __restrict__ blockOff,
                                                    int* __restrict__ rowStart, int n) {
    __shared__ int s[256];
    int t = threadIdx.x;
    int i = blockIdx.x * 256 + t;
    int v = i < n ? counts[i] : 0;
    s[t] = v;
    __syncthreads();
#pragma unroll
    for (int o = 1; o < 256; o <<= 1) {
        int add = t >= o ? s[t - o] : 0;
        __syncthreads();
        s[t] += add;
        __syncthreads();
    }
    if (i < n) rowStart[i] = blockOff[blockIdx.x] + s[t] - v;  // exclusive
}

// Scatter edge -> CSR slot, fusing the symmetric norm dinv[s]*dinv[d].
__global__ __launch_bounds__(256) void k_scatter(const int* __restrict__ src,
                                                 const int* __restrict__ dst,
                                                 const int* __restrict__ rowStart,
                                                 int* __restrict__ cursor,
                                                 const float* __restrict__ dinv,
                                                 int2* __restrict__ csr_ew, int E) {
    int e = blockIdx.x * 256 + threadIdx.x;
    if (e < E) {
        int s = src[e], d = dst[e];
        int pos = atomicAdd(&cursor[d], 1);
        float nw = dinv[s] * dinv[d];
        csr_ew[rowStart[d] + pos] = make_int2(s, __float_as_int(nw));
    }
}

struct h2x2 { __half2 a, b; };  // 8-byte packed 4x fp16

// Out[M,128](fp16) = (RELU ? relu(X) : X)[M,128](fp32) @ W[128,128](fp32)
// 256 threads, 128 rows/block; thread = 4x16 micro-tile; W in LDS (64KB).
template <int RELU>
__global__ __launch_bounds__(256) void k_gemm128(const float* __restrict__ X,
                                                 const float* __restrict__ W,
                                                 __half* __restrict__ Out, int M) {
    __shared__ float4 Wl[4096];  // [k=128][cgrp=32]
    const float4* W4 = reinterpret_cast<const float4*>(W);
    int tid = threadIdx.x;
#pragma unroll
    for (int i = 0; i < 16; i++) Wl[tid + 256 * i] = W4[tid + 256 * i];
    __syncthreads();

    int rgrp = tid >> 3, cq = tid & 7;
    long r0 = (long)blockIdx.x * 128 + rgrp * 4;
    float4 acc[4][4];
#pragma unroll
    for (int i = 0; i < 4; i++)
#pragma unroll
        for (int j = 0; j < 4; j++) acc[i][j] = make_float4(0.f, 0.f, 0.f, 0.f);

    const float4* X4 = reinterpret_cast<const float4*>(X);
    for (int kk = 0; kk < 32; ++kk) {
        float4 xv[4];
#pragma unroll
        for (int i = 0; i < 4; i++) {
            long r = r0 + i;
            if (r < M) {
                float4 v = X4[r * 32 + kk];
                if (RELU) {
                    v.x = fmaxf(v.x, 0.f); v.y = fmaxf(v.y, 0.f);
                    v.z = fmaxf(v.z, 0.f); v.w = fmaxf(v.w, 0.f);
                }
                xv[i] = v;
            } else {
                xv[i] = make_float4(0.f, 0.f, 0.f, 0.f);
            }
        }
#pragma unroll
        for (int l = 0; l < 4; l++) {
            float4 w[4];
#pragma unroll
            for (int j = 0; j < 4; j++) w[j] = Wl[(kk * 4 + l) * 32 + cq + 8 * j];
#pragma unroll
            for (int i = 0; i < 4; i++) {
                float xs = reinterpret_cast<const float*>(&xv[i])[l];
#pragma unroll
                for (int j = 0; j < 4; j++) {
                    acc[i][j].x = fmaf(xs, w[j].x, acc[i][j].x);
                    acc[i][j].y = fmaf(xs, w[j].y, acc[i][j].y);
                    acc[i][j].z = fmaf(xs, w[j].z, acc[i][j].z);
                    acc[i][j].w = fmaf(xs, w[j].w, acc[i][j].w);
                }
            }
        }
    }
    h2x2* O2 = reinterpret_cast<h2x2*>(Out);  // 32 h2x2 per row
#pragma unroll
    for (int i = 0; i < 4; i++) {
        long r = r0 + i;
        if (r < M) {
#pragma unroll
            for (int j = 0; j < 4; j++) {
                float4 v = acc[i][j];
                h2x2 pk;
                pk.a = __floats2half2_rn(v.x, v.y);
                pk.b = __floats2half2_rn(v.z, v.w);
                O2[r * 32 + cq + 8 * j] = pk;
            }
        }
    }
}

__device__ __forceinline__ void fma8(uint4 u, float w, float* a) {
    const __half2* h = reinterpret_cast<const __half2*>(&u);
#pragma unroll
    for (int k = 0; k < 4; ++k) {
        float2 f = __half22float2(h[k]);
        a[2 * k]     = fmaf(f.x, w, a[2 * k]);
        a[2 * k + 1] = fmaf(f.y, w, a[2 * k + 1]);
    }
}

// Wave per node, 4 edge-groups x 16 lanes. fp16 rows: ONE uint4 (16B) per
// lane covers the whole 256B row per group. Depth-2 register pipeline,
// mask-free rounds via weight=0 padding. Accumulate fp32; fuse self+bias.
__global__ __launch_bounds__(256) void k_gather_agg(const uint4* __restrict__ H2h,
                                                    const int* __restrict__ rowStart,
                                                    const int2* __restrict__ csr_ew,
                                                    const float* __restrict__ dinv,
                                                    const float* __restrict__ bias,
                                                    float4* __restrict__ out4, int n) {
    int node = blockIdx.x * 4 + (threadIdx.x >> 6);
    if (node >= n) return;
    int lane = threadIdx.x & 63;
    int g = lane >> 4, cl = lane & 15;
    int beg = rowStart[node], end = rowStart[node + 1];
    float dd = dinv[node];
    float a[8];
#pragma unroll
    for (int k = 0; k < 8; ++k) a[k] = 0.f;

    for (int j0 = beg; j0 < end; j0 += 64) {
        int m = end - j0;
        if (m > 64) m = 64;
        int idx = 0;
        float w = 0.f;
        if (lane < m) {
            int2 ew = csr_ew[j0 + lane];
            idx = ew.x;
            w = __int_as_float(ew.y);
        }
        int rounds = (m + 3) >> 2;
        int s = __shfl(idx, g, 64);
        float ws = __shfl(w, g, 64);
        uint4 p = H2h[(long)s * 16 + cl];
        for (int t = 1; t < rounds; ++t) {
            int e2 = t * 4 + g;
            int s2 = __shfl(idx, e2, 64);
            float ws2 = __shfl(w, e2, 64);
            uint4 q = H2h[(long)s2 * 16 + cl];   // issued before consuming p
            fma8(p, ws, a);
            p = q; ws = ws2;
        }
        fma8(p, ws, a);
    }
    // reduce across the 4 groups (offsets 16, 32)
#pragma unroll
    for (int off = 16; off < 64; off <<= 1) {
#pragma unroll
        for (int k = 0; k < 8; ++k) a[k] += __shfl_xor(a[k], off, 64);
    }
    if (g == 0) {
        uint4 h = H2h[(long)node * 16 + cl];
        const __half2* hh = reinterpret_cast<const __half2*>(&h);
        const float4* B4 = reinterpret_cast<const float4*>(bias);
        float4 b0 = B4[2 * cl], b1 = B4[2 * cl + 1];
        float w0 = dd * dd;   // self-loop norm = 1/deg
        float hf[8];
#pragma unroll
        for (int k = 0; k < 4; ++k) {
            float2 f = __half22float2(hh[k]);
            hf[2 * k] = f.x; hf[2 * k + 1] = f.y;
        }
        float4 o0, o1;
        o0.x = fmaf(hf[0], w0, a[0]) + b0.x; o0.y = fmaf(hf[1], w0, a[1]) + b0.y;
        o0.z = fmaf(hf[2], w0, a[2]) + b0.z; o0.w = fmaf(hf[3], w0, a[3]) + b0.w;
        o1.x = fmaf(hf[4], w0, a[4]) + b1.x; o1.y = fmaf(hf[5], w0, a[5]) + b1.y;
        o1.z = fmaf(hf[6], w0, a[6]) + b1.z; o1.w = fmaf(hf[7], w0, a[7]) + b1.w;
        out4[(long)node * 32 + 2 * cl] = o0;
        out4[(long)node * 32 + 2 * cl + 1] = o1;
    }
}

// 16 lanes per pair (4 pairs/wave, 8 rows in flight): fp32 Z2 rows.
__global__ __launch_bounds__(256) void k_score(const float4* __restrict__ Z4,
                                               const int* __restrict__ pe,
                                               const int* __restrict__ ne,
                                               float* __restrict__ out, int np) {
    int pair = blockIdx.x * 16 + (threadIdx.x >> 4);
    if (pair >= 2 * np) return;
    int cl = threadIdx.x & 15;
    const int* ei = pair < np ? pe : ne;
    int k = pair < np ? pair : pair - np;
    int a = ei[k], b = ei[k + np];
    float4 va0 = Z4[(long)a * 32 + cl], va1 = Z4[(long)a * 32 + cl + 16];
    float4 vb0 = Z4[(long)b * 32 + cl], vb1 = Z4[(long)b * 32 + cl + 16];
    float s = va0.x * vb0.x;
    s = fmaf(va0.y, vb0.y, s); s = fmaf(va0.z, vb0.z, s); s = fmaf(va0.w, vb0.w, s);
    s = fmaf(va1.x, vb1.x, s); s = fmaf(va1.y, vb1.y, s);
    s = fmaf(va1.z, vb1.z, s); s = fmaf(va1.w, vb1.w, s);
#pragma unroll
    for (int o = 1; o < 16; o <<= 1) s += __shfl_xor(s, o, 64);
    if (cl == 0) out[pair] = s;
}

extern "C" void kernel_launch(void* const* d_in, const int* in_sizes, int n_in,
                              void* d_out, int out_size, void* d_ws, size_t ws_size,
                              hipStream_t stream) {
    const float* x  = (const float*)d_in[0];
    const float* W1 = (const float*)d_in[1];
    const float* b1 = (const float*)d_in[2];
    const float* W2 = (const float*)d_in[3];
    const float* b2 = (const float*)d_in[4];
    const int* ei = (const int*)d_in[5];
    const int* pe = (const int*)d_in[6];
    const int* ne = (const int*)d_in[7];

    int n  = in_sizes[0] / 128;  // 50000
    int E  = in_sizes[5] / 2;    // 800000
    int np = in_sizes[6] / 2;    // 100000
    const int* src = ei;
    const int* dst = ei + E;

    // workspace layout (4-byte units; all sections 16B-aligned)
    int* counts   = (int*)d_ws;                 // n
    int* cursor   = counts + 50048;             // n   (adjacent: one zero pass)
    int* rowStart = cursor + 50048;             // n+1
    int* blockSum = rowStart + 50064;           // 256
    int* blockOff = blockSum + 256;             // 256
    int2* csr_ew  = (int2*)(blockOff + 256);    // E int2
    float* dinv   = (float*)(csr_ew + 800000);  // n
    __half* H     = (__half*)(dinv + 50000);    // n*128 fp16 (12.8 MB)
    float* Z      = (float*)(H + (size_t)n * 128);  // n*128 fp32
    float* out    = (float*)d_out;              // pos(np) ++ neg(np)

    dim3 B(256);
    int nb = (n + 255) / 256;  // 196 (<=256 required by k_scan_blocksums)

    // ---- CSR build + dinv ----
    k_zero<<<(2 * 50048 + 255) / 256, B, 0, stream>>>(counts, 2 * 50048);
    k_count<<<(E + 255) / 256, B, 0, stream>>>(dst, counts, E);
    k_prep<<<nb, B, 0, stream>>>(counts, dinv, blockSum, n);
    k_scan_blocksums<<<1, B, 0, stream>>>(blockSum, blockOff, rowStart, nb, n, E);
    k_scan_final<<<nb, B, 0, stream>>>(counts, blockOff, rowStart, n);
    k_scatter<<<(E + 255) / 256, B, 0, stream>>>(src, dst, rowStart, cursor, dinv, csr_ew, E);

    int gblk = (n + 127) / 128;
    int ablk = (n + 3) / 4;
    // layer 1: H1(fp16) = x@W1 ; Z1(fp32) = agg(H1)
    k_gemm128<0><<<gblk, B, 0, stream>>>(x, W1, H, n);
    k_gather_agg<<<ablk, B, 0, stream>>>((const uint4*)H, rowStart, csr_ew, dinv, b1, (float4*)Z, n);
    // layer 2: H2(fp16) = relu(Z1)@W2 ; Z2(fp32) = agg(H2)
    k_gemm128<1><<<gblk, B, 0, stream>>>(Z, W2, H, n);
    k_gather_agg<<<ablk, B, 0, stream>>>((const uint4*)H, rowStart, csr_ew, dinv, b2, (float4*)Z, n);
    // scoring
    k_score<<<(2 * np + 15) / 16, B, 0, stream>>>((const float4*)Z, pe, ne, out, np);
}

// Round 13
// 332.160 us; speedup vs baseline: 8.8597x; 1.0201x over previous
//
#include <hip/hip_runtime.h>
#include <hip/hip_bf16.h>
#include <hip/hip_fp16.h>

// GCN link predictor, round 13 (R12 resubmit; infra-only failure): MFMA split-fp16 GEMM.
//   CSR build (histogram -> scan -> scatter w/ fused edge weight) every launch
//   z1 = relu(gcn(x,W1,b1)); z2 = gcn(z1,W2,b2); scores = dot(z2[a], z2[b])
// GEMMs run on matrix cores: X split into hi+lo fp16, W pre-split+transposed;
// acc = Xhi*Whi + Xhi*Wlo + Xlo*Whi (fp32 acc) ~ fp32 GEMM precision (lo*lo
// term ~2e-7 rel dropped). H stored fp16 (halves random-gather traffic, R11).
// Z (agg outputs, score inputs) stay fp32 end-to-end.

using f16x8 = __attribute__((ext_vector_type(8))) _Float16;
using f32x4 = __attribute__((ext_vector_type(4))) float;

__global__ __launch_bounds__(256) void k_zero(int* p, int n) {
    int i = blockIdx.x * 256 + threadIdx.x;
    if (i < n) p[i] = 0;
}

__global__ __launch_bounds__(256) void k_count(const int* __restrict__ dst, int* counts, int E) {
    int e = blockIdx.x * 256 + threadIdx.x;
    if (e < E) atomicAdd(&counts[dst[e]], 1);
}

// dinv[i] = rsqrt(deg+1), plus per-block sum of counts for the scan.
__global__ __launch_bounds__(256) void k_prep(const int* __restrict__ counts,
                                              float* __restrict__ dinv,
                                              int* __restrict__ blockSum, int n) {
    __shared__ int s[256];
    int i = blockIdx.x * 256 + threadIdx.x;
    int c = i < n ? counts[i] : 0;
    if (i < n) dinv[i] = rsqrtf((float)c + 1.0f);  // +1 self-loop
    s[threadIdx.x] = c;
    __syncthreads();
#pragma unroll
    for (int o = 128; o > 0; o >>= 1) {
        if (threadIdx.x < o) s[threadIdx.x] += s[threadIdx.x + o];
        __syncthreads();
    }
    if (threadIdx.x == 0) blockSum[blockIdx.x] = s[0];
}

__global__ __launch_bounds__(256) void k_scan_blocksums(const int* __restrict__ blockSum,
                                                        int* __restrict__ blockOff,
                                                        int* __restrict__ rowStart,
                                                        int nb, int n, int E) {
    __shared__ int s[256];
    int t = threadIdx.x;
    int v = t < nb ? blockSum[t] : 0;
    s[t] = v;
    __syncthreads();
#pragma unroll
    for (int o = 1; o < 256; o <<= 1) {   // Hillis-Steele inclusive
        int add = t >= o ? s[t - o] : 0;
        __syncthreads();
        s[t] += add;
        __syncthreads();
    }
    if (t < nb) blockOff[t] = s[t] - v;   // exclusive
    if (t == 0) rowStart[n] = E;
}

__global__ __launch_bounds__(256) void k_scan_final(const int* __restrict__ counts,
                                                    const int* __restrict__ blockOff,
                                                    int* __restrict__ rowStart, int n) {
    __shared__ int s[256];
    int t = threadIdx.x;
    int i = blockIdx.x * 256 + t;
    int v = i < n ? counts[i] : 0;
    s[t] = v;
    __syncthreads();
#pragma unroll
    for (int o = 1; o < 256; o <<= 1) {
        int add = t >= o ? s[t - o] : 0;
        __syncthreads();
        s[t] += add;
        __syncthreads();
    }
    if (i < n) rowStart[i] = blockOff[blockIdx.x] + s[t] - v;  // exclusive
}

// Scatter edge -> CSR slot, fusing the symmetric norm dinv[s]*dinv[d].
__global__ __launch_bounds__(256) void k_scatter(const int* __restrict__ src,
                                                 const int* __restrict__ dst,
                                                 const int* __restrict__ rowStart,
                                                 int* __restrict__ cursor,
                                                 const float* __restrict__ dinv,
                                                 int2* __restrict__ csr_ew, int E) {
    int e = blockIdx.x * 256 + threadIdx.x;
    if (e < E) {
        int s = src[e], d = dst[e];
        int pos = atomicAdd(&cursor[d], 1);
        float nw = dinv[s] * dinv[d];
        csr_ew[rowStart[d] + pos] = make_int2(s, __float_as_int(nw));
    }
}

// Split W[128k][128n] fp32 -> Wt_hi/Wt_lo[n][k] fp16 (transposed for
// contiguous B-fragment loads).
__global__ __launch_bounds__(256) void k_wsplit(const float* __restrict__ W,
                                                _Float16* __restrict__ hi,
                                                _Float16* __restrict__ lo) {
    int i = blockIdx.x * 256 + threadIdx.x;  // 16384
    int k = i >> 7, n2 = i & 127;
    float w = W[i];
    _Float16 h = (_Float16)w;
    hi[n2 * 128 + k] = h;
    lo[n2 * 128 + k] = (_Float16)(w - (float)h);
}

// H[M,128](fp16) = (RELU ? relu(X) : X)[M,128](fp32) @ W[128,128]
// One wave per 16 rows (M must be divisible by 16; 50000 = 16*3125).
// mfma_f32_16x16x32_f16 fragments (m89-verified mapping):
//   A: row = lane&15, k = (lane>>4)*8 + j
//   B: col = lane&15, k = (lane>>4)*8 + j   (Wt is [n][k] -> 16B contiguous)
//   D: col = lane&15, row = (lane>>4)*4 + reg
template <int RELU>
__global__ __launch_bounds__(256) void k_gemm_mfma(const float* __restrict__ X,
                                                   const _Float16* __restrict__ Bt_hi,
                                                   const _Float16* __restrict__ Bt_lo,
                                                   _Float16* __restrict__ Out, int M) {
    int wid = blockIdx.x * 4 + (threadIdx.x >> 6);
    long r0 = (long)wid * 16;
    if (r0 >= M) return;
    int l = threadIdx.x & 63;
    int col = l & 15;   // A-row / B-col / D-col selector
    int kb = l >> 4;    // k-block 0..3

    // A fragments: row r0+col, k = s*32 + kb*8 + j  (8 fp32 -> hi/lo fp16)
    const float4* Xr = reinterpret_cast<const float4*>(X) + (r0 + col) * 32;
    f16x8 a_hi[4], a_lo[4];
#pragma unroll
    for (int s = 0; s < 4; ++s) {
        float4 f0 = Xr[s * 8 + kb * 2];
        float4 f1 = Xr[s * 8 + kb * 2 + 1];
        float v[8] = {f0.x, f0.y, f0.z, f0.w, f1.x, f1.y, f1.z, f1.w};
#pragma unroll
        for (int j = 0; j < 8; ++j) {
            float f = RELU ? fmaxf(v[j], 0.f) : v[j];
            _Float16 h = (_Float16)f;
            a_hi[s][j] = h;
            a_lo[s][j] = (_Float16)(f - (float)h);
        }
    }

    const f16x8* Bh = reinterpret_cast<const f16x8*>(Bt_hi);
    const f16x8* Bl = reinterpret_cast<const f16x8*>(Bt_lo);
    f32x4 acc[8];
#pragma unroll
    for (int jt = 0; jt < 8; ++jt) acc[jt] = (f32x4){0.f, 0.f, 0.f, 0.f};

#pragma unroll
    for (int jt = 0; jt < 8; ++jt) {
#pragma unroll
        for (int s = 0; s < 4; ++s) {
            int bi = (jt * 16 + col) * 16 + s * 4 + kb;  // [n][k] / 8
            f16x8 bh = Bh[bi];
            f16x8 bl = Bl[bi];
            acc[jt] = __builtin_amdgcn_mfma_f32_16x16x32_f16(a_hi[s], bh, acc[jt], 0, 0, 0);
            acc[jt] = __builtin_amdgcn_mfma_f32_16x16x32_f16(a_lo[s], bh, acc[jt], 0, 0, 0);
            acc[jt] = __builtin_amdgcn_mfma_f32_16x16x32_f16(a_hi[s], bl, acc[jt], 0, 0, 0);
        }
    }

    // store: D[row=kb*4+r][col] for each n-tile jt
#pragma unroll
    for (int jt = 0; jt < 8; ++jt) {
#pragma unroll
        for (int r = 0; r < 4; ++r) {
            Out[(r0 + kb * 4 + r) * 128 + jt * 16 + col] = (_Float16)acc[jt][r];
        }
    }
}

__device__ __forceinline__ void fma8(uint4 u, float w, float* a) {
    const __half2* h = reinterpret_cast<const __half2*>(&u);
#pragma unroll
    for (int k = 0; k < 4; ++k) {
        float2 f = __half22float2(h[k]);
        a[2 * k]     = fmaf(f.x, w, a[2 * k]);
        a[2 * k + 1] = fmaf(f.y, w, a[2 * k + 1]);
    }
}

// Wave per node, 4 edge-groups x 16 lanes. fp16 rows: ONE uint4 (16B) per
// lane covers the whole 256B row per group. Depth-2 register pipeline,
// mask-free rounds via weight=0 padding. Accumulate fp32; fuse self+bias.
__global__ __launch_bounds__(256) void k_gather_agg(const uint4* __restrict__ H2h,
                                                    const int* __restrict__ rowStart,
                                                    const int2* __restrict__ csr_ew,
                                                    const float* __restrict__ dinv,
                                                    const float* __restrict__ bias,
                                                    float4* __restrict__ out4, int n) {
    int node = blockIdx.x * 4 + (threadIdx.x >> 6);
    if (node >= n) return;
    int lane = threadIdx.x & 63;
    int g = lane >> 4, cl = lane & 15;
    int beg = rowStart[node], end = rowStart[node + 1];
    float dd = dinv[node];
    float a[8];
#pragma unroll
    for (int k = 0; k < 8; ++k) a[k] = 0.f;

    for (int j0 = beg; j0 < end; j0 += 64) {
        int m = end - j0;
        if (m > 64) m = 64;
        int idx = 0;
        float w = 0.f;
        if (lane < m) {
            int2 ew = csr_ew[j0 + lane];
            idx = ew.x;
            w = __int_as_float(ew.y);
        }
        int rounds = (m + 3) >> 2;
        int s = __shfl(idx, g, 64);
        float ws = __shfl(w, g, 64);
        uint4 p = H2h[(long)s * 16 + cl];
        for (int t = 1; t < rounds; ++t) {
            int e2 = t * 4 + g;
            int s2 = __shfl(idx, e2, 64);
            float ws2 = __shfl(w, e2, 64);
            uint4 q = H2h[(long)s2 * 16 + cl];   // issued before consuming p
            fma8(p, ws, a);
            p = q; ws = ws2;
        }
        fma8(p, ws, a);
    }
    // reduce across the 4 groups (offsets 16, 32)
#pragma unroll
    for (int off = 16; off < 64; off <<= 1) {
#pragma unroll
        for (int k = 0; k < 8; ++k) a[k] += __shfl_xor(a[k], off, 64);
    }
    if (g == 0) {
        uint4 h = H2h[(long)node * 16 + cl];
        const __half2* hh = reinterpret_cast<const __half2*>(&h);
        const float4* B4 = reinterpret_cast<const float4*>(bias);
        float4 b0 = B4[2 * cl], b1 = B4[2 * cl + 1];
        float w0 = dd * dd;   // self-loop norm = 1/deg
        float hf[8];
#pragma unroll
        for (int k = 0; k < 4; ++k) {
            float2 f = __half22float2(hh[k]);
            hf[2 * k] = f.x; hf[2 * k + 1] = f.y;
        }
        float4 o0, o1;
        o0.x = fmaf(hf[0], w0, a[0]) + b0.x; o0.y = fmaf(hf[1], w0, a[1]) + b0.y;
        o0.z = fmaf(hf[2], w0, a[2]) + b0.z; o0.w = fmaf(hf[3], w0, a[3]) + b0.w;
        o1.x = fmaf(hf[4], w0, a[4]) + b1.x; o1.y = fmaf(hf[5], w0, a[5]) + b1.y;
        o1.z = fmaf(hf[6], w0, a[6]) + b1.z; o1.w = fmaf(hf[7], w0, a[7]) + b1.w;
        out4[(long)node * 32 + 2 * cl] = o0;
        out4[(long)node * 32 + 2 * cl + 1] = o1;
    }
}

// 16 lanes per pair (4 pairs/wave, 8 rows in flight): fp32 Z2 rows.
__global__ __launch_bounds__(256) void k_score(const float4* __restrict__ Z4,
                                               const int* __restrict__ pe,
                                               const int* __restrict__ ne,
                                               float* __restrict__ out, int np) {
    int pair = blockIdx.x * 16 + (threadIdx.x >> 4);
    if (pair >= 2 * np) return;
    int cl = threadIdx.x & 15;
    const int* ei = pair < np ? pe : ne;
    int k = pair < np ? pair : pair - np;
    int a = ei[k], b = ei[k + np];
    float4 va0 = Z4[(long)a * 32 + cl], va1 = Z4[(long)a * 32 + cl + 16];
    float4 vb0 = Z4[(long)b * 32 + cl], vb1 = Z4[(long)b * 32 + cl + 16];
    float s = va0.x * vb0.x;
    s = fmaf(va0.y, vb0.y, s); s = fmaf(va0.z, vb0.z, s); s = fmaf(va0.w, vb0.w, s);
    s = fmaf(va1.x, vb1.x, s); s = fmaf(va1.y, vb1.y, s);
    s = fmaf(va1.z, vb1.z, s); s = fmaf(va1.w, vb1.w, s);
#pragma unroll
    for (int o = 1; o < 16; o <<= 1) s += __shfl_xor(s, o, 64);
    if (cl == 0) out[pair] = s;
}

extern "C" void kernel_launch(void* const* d_in, const int* in_sizes, int n_in,
                              void* d_out, int out_size, void* d_ws, size_t ws_size,
                              hipStream_t stream) {
    const float* x  = (const float*)d_in[0];
    const float* W1 = (const float*)d_in[1];
    const float* b1 = (const float*)d_in[2];
    const float* W2 = (const float*)d_in[3];
    const float* b2 = (const float*)d_in[4];
    const int* ei = (const int*)d_in[5];
    const int* pe = (const int*)d_in[6];
    const int* ne = (const int*)d_in[7];

    int n  = in_sizes[0] / 128;  // 50000 (divisible by 16)
    int E  = in_sizes[5] / 2;    // 800000
    int np = in_sizes[6] / 2;    // 100000
    const int* src = ei;
    const int* dst = ei + E;

    // workspace layout (4-byte units; all sections 16B-aligned)
    int* counts   = (int*)d_ws;                 // n
    int* cursor   = counts + 50048;             // n   (adjacent: one zero pass)
    int* rowStart = cursor + 50048;             // n+1
    int* blockSum = rowStart + 50064;           // 256
    int* blockOff = blockSum + 256;             // 256
    int2* csr_ew  = (int2*)(blockOff + 256);    // E int2
    float* dinv   = (float*)(csr_ew + 800000);  // n
    _Float16* Wt1h = (_Float16*)(dinv + 50000); // 16384 halfs each
    _Float16* Wt1l = Wt1h + 16384;
    _Float16* Wt2h = Wt1l + 16384;
    _Float16* Wt2l = Wt2h + 16384;
    _Float16* H    = Wt2l + 16384;              // n*128 fp16 (12.8 MB)
    float* Z       = (float*)(H + (size_t)n * 128);  // n*128 fp32
    float* out     = (float*)d_out;             // pos(np) ++ neg(np)

    dim3 B(256);
    int nb = (n + 255) / 256;  // 196 (<=256 required by k_scan_blocksums)

    // ---- CSR build + dinv + W splits ----
    k_zero<<<(2 * 50048 + 255) / 256, B, 0, stream>>>(counts, 2 * 50048);
    k_count<<<(E + 255) / 256, B, 0, stream>>>(dst, counts, E);
    k_prep<<<nb, B, 0, stream>>>(counts, dinv, blockSum, n);
    k_scan_blocksums<<<1, B, 0, stream>>>(blockSum, blockOff, rowStart, nb, n, E);
    k_scan_final<<<nb, B, 0, stream>>>(counts, blockOff, rowStart, n);
    k_scatter<<<(E + 255) / 256, B, 0, stream>>>(src, dst, rowStart, cursor, dinv, csr_ew, E);
    k_wsplit<<<64, B, 0, stream>>>(W1, Wt1h, Wt1l);
    k_wsplit<<<64, B, 0, stream>>>(W2, Wt2h, Wt2l);

    int gblk = (n / 16 + 3) / 4;  // 782 blocks (4 waves each)
    int ablk = (n + 3) / 4;
    // layer 1: H1(fp16) = x@W1 ; Z1(fp32) = agg(H1)
    k_gemm_mfma<0><<<gblk, B, 0, stream>>>(x, Wt1h, Wt1l, H, n);
    k_gather_agg<<<ablk, B, 0, stream>>>((const uint4*)H, rowStart, csr_ew, dinv, b1, (float4*)Z, n);
    // layer 2: H2(fp16) = relu(Z1)@W2 ; Z2(fp32) = agg(H2)
    k_gemm_mfma<1><<<gblk, B, 0, stream>>>(Z, Wt2h, Wt2l, H, n);
    k_gather_agg<<<ablk, B, 0, stream>>>((const uint4*)H, rowStart, csr_ew, dinv, b2, (float4*)Z, n);
    // scoring
    k_score<<<(2 * np + 15) / 16, B, 0, stream>>>((const float4*)Z, pe, ne, out, np);
}